// Round 4
// baseline (170.245 us; speedup 1.0000x reference)
//
#include <hip/hip_runtime.h>

#define NN 50000
#define KK 20

// Pool repacked CHANNEL-GROUP-major for XCD slicing:
// g_pool[group][side][node*16 + ch] bf16; per-group slice (A+B) = 3.2 MB,
// fits one XCD's 4 MiB L2. group = bx & 3 pins group g to XCDs {g, g+4}
// (round-robin blockIdx->XCD mapping).
__device__ __align__(256) ushort g_pool[4][2][NN * 16];   // 12.8 MB
__device__ __align__(256) float  g_sup[NN * KK];          // 4 MB

static __device__ __forceinline__ ushort f2bf(float f) {
    unsigned int u = __float_as_uint(f);
    unsigned int r = (u + 0x7FFFu + ((u >> 16) & 1u)) >> 16;   // RNE
    return (ushort)r;
}
static __device__ __forceinline__ float bfl(unsigned int u) {   // low bf16 -> f32
    return __uint_as_float(u << 16);
}
static __device__ __forceinline__ float bfh(unsigned int u) {   // high bf16 -> f32
    return __uint_as_float(u & 0xffff0000u);
}

// ---------------------------------------------------------------------------
// Kernel 1: GEMM + sup precompute (structure unchanged from R2/R3; only the
// pool-store indexing changed to the group-major layout).
// ---------------------------------------------------------------------------
__global__ __launch_bounds__(256) void prep_kernel(
    const float* __restrict__ x,    // [64][NN]
    const float* __restrict__ W,    // [64][128]
    const float* __restrict__ b,    // [64]
    const float* __restrict__ dis,  // [NN][KK]
    const float* __restrict__ att_w,// [KK]
    const float* __restrict__ att_b)// [1]
{
    __shared__ float At[64][66];    // W1-W2, transposed
    __shared__ float Bt[64][66];    // W2, transposed
    __shared__ float xt[64][132];   // x tile, 128 nodes
    __shared__ float disL[128 * KK];
    __shared__ float scalerL[128];

    const int t  = threadIdx.x;
    const int n0 = blockIdx.x * 128;     // grid 391; tail block has 80 valid

    for (int i = t; i < 64 * 64; i += 256) {
        int c = i >> 6, ci = i & 63;
        float w1 = W[c * 128 + ci];
        float w2 = W[c * 128 + 64 + ci];
        At[ci][c] = w1 - w2;
        Bt[ci][c] = w2;
    }
    {
        const int q  = t & 31;           // float4 index within the 128 nodes
        const int cb = t >> 5;           // 0..7
        const float4* x4 = (const float4*)x;   // [64][12500] float4
        const int nq = (n0 >> 2) + q;
        #pragma unroll
        for (int i = 0; i < 8; i++) {
            const int ci = cb * 8 + i;
            float4 v = (nq < 12500) ? x4[ci * 12500 + nq]
                                    : float4{0.f, 0.f, 0.f, 0.f};
            *(float4*)&xt[ci][q * 4] = v;
        }
    }
    for (int i = t; i < 128 * KK; i += 256) {
        const int gi = n0 * KK + i;
        disL[i] = (gi < NN * KK) ? dis[gi] : 0.f;
    }
    __syncthreads();

    // scaler[n] = tanh(att_w . dis[n] + att_b) + 1 = 2*sigmoid(2z)
    if (t < 128) {
        float z = att_b[0];
        #pragma unroll
        for (int k = 0; k < KK; k++) z += att_w[k] * disL[t * KK + k];
        scalerL[t] = 2.f / (1.f + __expf(-2.f * z));
    }
    __syncthreads();

    // sup[n][k] = 2*sigmoid(-dis*scaler)
    for (int i = t; i < 128 * KK; i += 256) {
        const int gi = n0 * KK + i;
        if (gi < NN * KK)
            g_sup[gi] = 2.f / (1.f + __expf(disL[i] * scalerL[i / KK]));
    }

    // ---- GEMM: 2 adjacent channels x 16 nodes per thread ----
    const int c2 = t & 31;     // channel pair: channels 2*c2, 2*c2+1
    const int g  = t >> 5;     // node group 0..7 -> nodes g*16 .. g*16+15

    float aA0[16], aA1[16], aB0[16], aB1[16];
    #pragma unroll
    for (int j = 0; j < 16; j++) { aA0[j]=0.f; aA1[j]=0.f; aB0[j]=0.f; aB1[j]=0.f; }

    for (int ci = 0; ci < 64; ci++) {
        const float2 a  = *(const float2*)&At[ci][c2 * 2];
        const float2 w2 = *(const float2*)&Bt[ci][c2 * 2];
        const float4* xr = (const float4*)&xt[ci][g * 16];
        #pragma unroll
        for (int q = 0; q < 4; q++) {
            float4 xv = xr[q];
            aA0[q*4+0] += a.x*xv.x;  aA1[q*4+0] += a.y*xv.x;
            aB0[q*4+0] += w2.x*xv.x; aB1[q*4+0] += w2.y*xv.x;
            aA0[q*4+1] += a.x*xv.y;  aA1[q*4+1] += a.y*xv.y;
            aB0[q*4+1] += w2.x*xv.y; aB1[q*4+1] += w2.y*xv.y;
            aA0[q*4+2] += a.x*xv.z;  aA1[q*4+2] += a.y*xv.z;
            aB0[q*4+2] += w2.x*xv.z; aB1[q*4+2] += w2.y*xv.z;
            aA0[q*4+3] += a.x*xv.w;  aA1[q*4+3] += a.y*xv.w;
            aB0[q*4+3] += w2.x*xv.w; aB1[q*4+3] += w2.y*xv.w;
        }
    }

    // stores: channel pair c2 -> group gq = c2>>3, pair-in-group pp = c2&7
    const float b0 = b[c2 * 2], b1 = b[c2 * 2 + 1];
    const int gq = c2 >> 3;
    const int pp = c2 & 7;
    unsigned int* poolU = (unsigned int*)g_pool;   // planes of [NN][8] uints
    const size_t pa = (size_t)(gq * 2 + 0) * NN * 8;
    const size_t pb = (size_t)(gq * 2 + 1) * NN * 8;
    #pragma unroll
    for (int j = 0; j < 16; j++) {
        const int n = n0 + g * 16 + j;
        if (n < NN) {
            poolU[pa + (size_t)n * 8 + pp] = (unsigned int)f2bf(aA0[j] + b0)
                                           | ((unsigned int)f2bf(aA1[j] + b1) << 16);
            poolU[pb + (size_t)n * 8 + pp] = (unsigned int)f2bf(aB0[j])
                                           | ((unsigned int)f2bf(aB1[j]) << 16);
        }
    }
}

// ---------------------------------------------------------------------------
// Kernel 2: XCD-sliced gather. Block handles ONE channel group (16 ch) x 16
// nodes; group = bx & 3 -> XCDs {g, g+4} each keep the 3.2 MB group slice
// L2-resident. Per node: 16 edge slots x 4 channel-quads, 2 rounds (slots
// 20..31 are pads: offset 0, sup 0 -> contribute exactly 0 to the max).
// ---------------------------------------------------------------------------
__global__ __launch_bounds__(256) void edge_kernel(
    const int* __restrict__ ej,      // edge_index[0] : [NN][KK]  (x_j -> B side)
    const int* __restrict__ ei,      // edge_index[1] : [NN][KK]  (x_i -> A side)
    float* __restrict__ out)         // [64][NN]
{
    __shared__ float tile[16][20];   // [node][16 ch], row 80 B (16B-aligned)

    const int t    = threadIdx.x;
    const int lane = t & 63;
    const int w    = t >> 6;            // wave 0..3
    const int g2   = lane >> 2;         // edge slot 0..15
    const int q    = lane & 3;          // channel quad 0..3 (4 ch of the group)
    const int bx   = blockIdx.x;        // 0..12499
    const int grp  = bx & 3;            // channel group, pinned to XCD pair
    const int n0   = (bx >> 2) * 16;    // node block
    const int nb   = n0 + w * 4;

    const char* pA = (const char*)&g_pool[grp][0][0];
    const char* pB = (const char*)&g_pool[grp][1][0];

    int offI[4], offJ[4]; float sup4[4];
    #pragma unroll
    for (int s = 0; s < 4; s++) {
        const int n = nb + s;
        int ii = 0, jj = 0; float sp = 0.f;
        if (lane < KK) {
            ii = __builtin_nontemporal_load(&ei[n * KK + lane]);
            jj = __builtin_nontemporal_load(&ej[n * KK + lane]);
            sp = __builtin_nontemporal_load(&g_sup[n * KK + lane]);
        }
        offI[s] = ii << 5;      // byte offset: node * 32 (16 ch x 2 B)
        offJ[s] = jj << 5;
        sup4[s] = sp;           // 0 for lanes >= 20 -> pad slots contribute 0
    }

    #pragma unroll
    for (int s = 0; s < 4; s++) {
        float4 m = {0.f, 0.f, 0.f, 0.f};
        #pragma unroll
        for (int r = 0; r < 2; r++) {
            const int   src = r * 16 + g2;      // 0..31; 20..31 are zero-pads
            const int   oi  = __shfl(offI[s], src);
            const int   oj  = __shfl(offJ[s], src);
            const float sp  = __shfl(sup4[s], src);
            const uint2 a   = *(const uint2*)(pA + oi + q * 8);
            const uint2 bb  = *(const uint2*)(pB + oj + q * 8);
            float v;
            v = fmaxf(bfl(a.x) + bfl(bb.x), 0.f) * sp;  m.x = fmaxf(m.x, v);
            v = fmaxf(bfh(a.x) + bfh(bb.x), 0.f) * sp;  m.y = fmaxf(m.y, v);
            v = fmaxf(bfl(a.y) + bfl(bb.y), 0.f) * sp;  m.z = fmaxf(m.z, v);
            v = fmaxf(bfh(a.y) + bfh(bb.y), 0.f) * sp;  m.w = fmaxf(m.w, v);
        }
        // reduce over 16 slots = lane bits 2..5
        #pragma unroll
        for (int mask = 4; mask <= 32; mask <<= 1) {
            m.x = fmaxf(m.x, __shfl_xor(m.x, mask));
            m.y = fmaxf(m.y, __shfl_xor(m.y, mask));
            m.z = fmaxf(m.z, __shfl_xor(m.z, mask));
            m.w = fmaxf(m.w, __shfl_xor(m.w, mask));
        }
        if (g2 == 0) *(float4*)&tile[w * 4 + s][q * 4] = m;
    }
    __syncthreads();

    {
        const int c  = t >> 4;      // 0..15 channel within group
        const int nl = t & 15;      // node within block
        __builtin_nontemporal_store(tile[nl][c],
                                    &out[(size_t)(grp * 16 + c) * NN + n0 + nl]);
    }
}

extern "C" void kernel_launch(void* const* d_in, const int* in_sizes, int n_in,
                              void* d_out, int out_size, void* d_ws, size_t ws_size,
                              hipStream_t stream) {
    const float* x     = (const float*)d_in[0];
    const int*   e     = (const int*)d_in[1];    // [2][NN][KK]
    const float* dis   = (const float*)d_in[2];
    const float* W     = (const float*)d_in[3];
    const float* b     = (const float*)d_in[4];
    const float* att_w = (const float*)d_in[5];
    const float* att_b = (const float*)d_in[6];
    float* out = (float*)d_out;

    (void)d_ws; (void)ws_size;   // intentionally unused: static __device__ scratch

    prep_kernel<<<(NN + 127) / 128, 256, 0, stream>>>(x, W, b, dis, att_w, att_b);
    edge_kernel<<<4 * (NN / 16), 256, 0, stream>>>(e, e + NN * KK, out);
}

// Round 5
// 145.916 us; speedup vs baseline: 1.1667x; 1.1667x over previous
//
#include <hip/hip_runtime.h>

#define NN 50000
#define KK 20

// Pool in TWO channel groups of 32 for XCD slicing: g_pool[grp][side][n*32+ch]
// bf16. Slice (A+B) = 6.4 MB; grp = bx&1 pins grp 0 -> XCDs {0,2,4,6},
// grp 1 -> {1,3,5,7} (bx%8 round-robin mapping validated by R4's FETCH drop).
__device__ __align__(256) ushort g_pool[2][2][NN * 32];   // 12.8 MB
__device__ __align__(256) float  g_sup[NN * KK];          // 4 MB

static __device__ __forceinline__ ushort f2bf(float f) {
    unsigned int u = __float_as_uint(f);
    unsigned int r = (u + 0x7FFFu + ((u >> 16) & 1u)) >> 16;   // RNE
    return (ushort)r;
}
static __device__ __forceinline__ float bfl(unsigned int u) {   // low bf16 -> f32
    return __uint_as_float(u << 16);
}
static __device__ __forceinline__ float bfh(unsigned int u) {   // high bf16 -> f32
    return __uint_as_float(u & 0xffff0000u);
}

// ---------------------------------------------------------------------------
// Kernel 1: GEMM + sup precompute (structure unchanged since R2; only the
// pool-store indexing targets the 2-group layout).
// ---------------------------------------------------------------------------
__global__ __launch_bounds__(256) void prep_kernel(
    const float* __restrict__ x,    // [64][NN]
    const float* __restrict__ W,    // [64][128]
    const float* __restrict__ b,    // [64]
    const float* __restrict__ dis,  // [NN][KK]
    const float* __restrict__ att_w,// [KK]
    const float* __restrict__ att_b)// [1]
{
    __shared__ float At[64][66];    // W1-W2, transposed
    __shared__ float Bt[64][66];    // W2, transposed
    __shared__ float xt[64][132];   // x tile, 128 nodes
    __shared__ float disL[128 * KK];
    __shared__ float scalerL[128];

    const int t  = threadIdx.x;
    const int n0 = blockIdx.x * 128;     // grid 391; tail block has 80 valid

    for (int i = t; i < 64 * 64; i += 256) {
        int c = i >> 6, ci = i & 63;
        float w1 = W[c * 128 + ci];
        float w2 = W[c * 128 + 64 + ci];
        At[ci][c] = w1 - w2;
        Bt[ci][c] = w2;
    }
    {
        const int q  = t & 31;           // float4 index within the 128 nodes
        const int cb = t >> 5;           // 0..7
        const float4* x4 = (const float4*)x;   // [64][12500] float4
        const int nq = (n0 >> 2) + q;
        #pragma unroll
        for (int i = 0; i < 8; i++) {
            const int ci = cb * 8 + i;
            float4 v = (nq < 12500) ? x4[ci * 12500 + nq]
                                    : float4{0.f, 0.f, 0.f, 0.f};
            *(float4*)&xt[ci][q * 4] = v;
        }
    }
    for (int i = t; i < 128 * KK; i += 256) {
        const int gi = n0 * KK + i;
        disL[i] = (gi < NN * KK) ? dis[gi] : 0.f;
    }
    __syncthreads();

    // scaler[n] = tanh(att_w . dis[n] + att_b) + 1 = 2*sigmoid(2z)
    if (t < 128) {
        float z = att_b[0];
        #pragma unroll
        for (int k = 0; k < KK; k++) z += att_w[k] * disL[t * KK + k];
        scalerL[t] = 2.f / (1.f + __expf(-2.f * z));
    }
    __syncthreads();

    // sup[n][k] = 2*sigmoid(-dis*scaler)
    for (int i = t; i < 128 * KK; i += 256) {
        const int gi = n0 * KK + i;
        if (gi < NN * KK)
            g_sup[gi] = 2.f / (1.f + __expf(disL[i] * scalerL[i / KK]));
    }

    // ---- GEMM: 2 adjacent channels x 16 nodes per thread ----
    const int c2 = t & 31;     // channel pair: channels 2*c2, 2*c2+1
    const int g  = t >> 5;     // node group 0..7 -> nodes g*16 .. g*16+15

    float aA0[16], aA1[16], aB0[16], aB1[16];
    #pragma unroll
    for (int j = 0; j < 16; j++) { aA0[j]=0.f; aA1[j]=0.f; aB0[j]=0.f; aB1[j]=0.f; }

    for (int ci = 0; ci < 64; ci++) {
        const float2 a  = *(const float2*)&At[ci][c2 * 2];
        const float2 w2 = *(const float2*)&Bt[ci][c2 * 2];
        const float4* xr = (const float4*)&xt[ci][g * 16];
        #pragma unroll
        for (int q = 0; q < 4; q++) {
            float4 xv = xr[q];
            aA0[q*4+0] += a.x*xv.x;  aA1[q*4+0] += a.y*xv.x;
            aB0[q*4+0] += w2.x*xv.x; aB1[q*4+0] += w2.y*xv.x;
            aA0[q*4+1] += a.x*xv.y;  aA1[q*4+1] += a.y*xv.y;
            aB0[q*4+1] += w2.x*xv.y; aB1[q*4+1] += w2.y*xv.y;
            aA0[q*4+2] += a.x*xv.z;  aA1[q*4+2] += a.y*xv.z;
            aB0[q*4+2] += w2.x*xv.z; aB1[q*4+2] += w2.y*xv.z;
            aA0[q*4+3] += a.x*xv.w;  aA1[q*4+3] += a.y*xv.w;
            aB0[q*4+3] += w2.x*xv.w; aB1[q*4+3] += w2.y*xv.w;
        }
    }

    // stores: channel pair c2 -> group gq = c2>>4 (ch 0-31 / 32-63), pair pp
    const float b0 = b[c2 * 2], b1 = b[c2 * 2 + 1];
    const int gq = c2 >> 4;
    const int pp = c2 & 15;
    unsigned int* poolU = (unsigned int*)g_pool;   // planes of [NN][16] uints
    const size_t pa = (size_t)(gq * 2 + 0) * NN * 16;
    const size_t pb = (size_t)(gq * 2 + 1) * NN * 16;
    #pragma unroll
    for (int j = 0; j < 16; j++) {
        const int n = n0 + g * 16 + j;
        if (n < NN) {
            poolU[pa + (size_t)n * 16 + pp] = (unsigned int)f2bf(aA0[j] + b0)
                                            | ((unsigned int)f2bf(aA1[j] + b1) << 16);
            poolU[pb + (size_t)n * 16 + pp] = (unsigned int)f2bf(aB0[j])
                                            | ((unsigned int)f2bf(aB1[j]) << 16);
        }
    }
}

// ---------------------------------------------------------------------------
// Kernel 2: pinned 2-way XCD-sliced gather with amortized overhead.
// Block = ONE group (32 ch) x 40 nodes (grid 2x1250, grp = bx&1 -> XCD pin).
// Per wave: 10 nodes; per node: 8 edge slots x 8 channel-quads (uint2/lane,
// 64 B = one sector per slot), 3 rounds (slots 20..23 pads: offset 0, sup 0).
// ReLU folded into the running max (m >= 0 invariant, sup >= 0).
// ---------------------------------------------------------------------------
__global__ __launch_bounds__(256) void edge_kernel(
    const int* __restrict__ ej,      // edge_index[0] : [NN][KK]  (x_j -> B side)
    const int* __restrict__ ei,      // edge_index[1] : [NN][KK]  (x_i -> A side)
    float* __restrict__ out)         // [64][NN]
{
    __shared__ float tile[40][36];   // [node][32 ch], 36-stride (conflict-light)

    const int t    = threadIdx.x;
    const int lane = t & 63;
    const int w    = t >> 6;            // wave 0..3
    const int slot = lane >> 3;         // edge slot 0..7
    const int q    = lane & 7;          // channel quad 0..7 (4 ch each)
    const int bx   = blockIdx.x;        // 0..2499
    const int grp  = bx & 1;            // channel group, pinned to XCD set
    const int n0   = (bx >> 1) * 40;    // node block (1250 blocks, exact)
    const int nb   = n0 + w * 10;

    const char* pA = (const char*)&g_pool[grp][0][0];
    const char* pB = (const char*)&g_pool[grp][1][0];

    int offI[10], offJ[10]; float sup10[10];
    #pragma unroll
    for (int s = 0; s < 10; s++) {
        const int n = nb + s;
        int ii = 0, jj = 0; float sp = 0.f;
        if (lane < KK) {
            ii = __builtin_nontemporal_load(&ei[n * KK + lane]);
            jj = __builtin_nontemporal_load(&ej[n * KK + lane]);
            sp = __builtin_nontemporal_load(&g_sup[n * KK + lane]);
        }
        offI[s] = ii << 6;      // byte offset: node * 64 (32 ch x 2 B)
        offJ[s] = jj << 6;
        sup10[s] = sp;          // 0 for lanes >= 20 -> pad slots contribute 0
    }

    #pragma unroll
    for (int s = 0; s < 10; s++) {
        float4 m = {0.f, 0.f, 0.f, 0.f};
        #pragma unroll
        for (int r = 0; r < 3; r++) {
            const int   src = r * 8 + slot;     // 0..23; 20..23 are zero-pads
            const int   oi  = __shfl(offI[s], src);
            const int   oj  = __shfl(offJ[s], src);
            const float sp  = __shfl(sup10[s], src);
            const uint2 a   = *(const uint2*)(pA + oi + q * 8);
            const uint2 bb  = *(const uint2*)(pB + oj + q * 8);
            // relu folded into max: m>=0 and sp>=0 => fmax(m, z*sp) == fmax(m, relu(z)*sp)
            m.x = fmaxf(m.x, (bfl(a.x) + bfl(bb.x)) * sp);
            m.y = fmaxf(m.y, (bfh(a.x) + bfh(bb.x)) * sp);
            m.z = fmaxf(m.z, (bfl(a.y) + bfl(bb.y)) * sp);
            m.w = fmaxf(m.w, (bfh(a.y) + bfh(bb.y)) * sp);
        }
        // reduce over 8 slots = lane bits 3..5
        #pragma unroll
        for (int mask = 8; mask <= 32; mask <<= 1) {
            m.x = fmaxf(m.x, __shfl_xor(m.x, mask));
            m.y = fmaxf(m.y, __shfl_xor(m.y, mask));
            m.z = fmaxf(m.z, __shfl_xor(m.z, mask));
            m.w = fmaxf(m.w, __shfl_xor(m.w, mask));
        }
        if (slot == 0) *(float4*)&tile[w * 10 + s][q * 4] = m;
    }
    __syncthreads();

    #pragma unroll
    for (int cn = 0; cn < 5; cn++) {
        const int c  = t >> 3;              // 0..31 channel within group
        const int nl = cn * 8 + (t & 7);    // 0..39 node within block
        __builtin_nontemporal_store(tile[nl][c],
                                    &out[(size_t)(grp * 32 + c) * NN + n0 + nl]);
    }
}

extern "C" void kernel_launch(void* const* d_in, const int* in_sizes, int n_in,
                              void* d_out, int out_size, void* d_ws, size_t ws_size,
                              hipStream_t stream) {
    const float* x     = (const float*)d_in[0];
    const int*   e     = (const int*)d_in[1];    // [2][NN][KK]
    const float* dis   = (const float*)d_in[2];
    const float* W     = (const float*)d_in[3];
    const float* b     = (const float*)d_in[4];
    const float* att_w = (const float*)d_in[5];
    const float* att_b = (const float*)d_in[6];
    float* out = (float*)d_out;

    (void)d_ws; (void)ws_size;   // intentionally unused: static __device__ scratch

    prep_kernel<<<(NN + 127) / 128, 256, 0, stream>>>(x, W, b, dis, att_w, att_b);
    edge_kernel<<<2 * (NN / 40), 256, 0, stream>>>(e, e + NN * KK, out);
}